// Round 4
// baseline (1859.993 us; speedup 1.0000x reference)
//
#include <hip/hip_runtime.h>
#include <hip/hip_bf16.h>
#include <math.h>

#define V_NODES 262144
#define NGRAPH  4096
#define FD      256
#define TSTEPS  2
#define NBLK    1024   // 4 blocks/CU on 256 CUs — co-resident by construction

typedef unsigned short u16;
typedef __attribute__((ext_vector_type(8))) short short8;
typedef __attribute__((ext_vector_type(4))) float f32x4;

__device__ __forceinline__ float bf2f(u16 u) {
  union { unsigned int i; float f; } x; x.i = ((unsigned int)u) << 16; return x.f;
}
__device__ __forceinline__ u16 f2bf(float f) {
  union { unsigned int i; float f; } x; x.f = f;
  unsigned int r = x.i + 0x7FFFu + ((x.i >> 16) & 1u);
  return (u16)(r >> 16);
}
__device__ __forceinline__ unsigned int pkbf(float a, float b) {
  return (unsigned int)f2bf(a) | ((unsigned int)f2bf(b) << 16);
}
__device__ __forceinline__ float softplus2(float x) {
  return fmaxf(x, 0.0f) + log1pf(__expf(-fabsf(x))) - 0.69314718056f;
}

// single-use grid barrier (bar[id] zeroed by hipMemsetAsync before each launch)
__device__ __forceinline__ void gsync(int* bar, int id) {
  __syncthreads();
  if (threadIdx.x == 0) {
    __threadfence();
    __hip_atomic_fetch_add(&bar[id], 1, __ATOMIC_ACQ_REL, __HIP_MEMORY_SCOPE_AGENT);
    while (__hip_atomic_load(&bar[id], __ATOMIC_ACQUIRE, __HIP_MEMORY_SCOPE_AGENT) < NBLK)
      __builtin_amdgcn_s_sleep(2);
    __threadfence();
  }
  __syncthreads();
}

// 16x16 MFMA tile over K=256: X,W pre-offset to (row r, q*8)
__device__ __forceinline__ f32x4 mm256(const u16* __restrict__ X,
                                       const u16* __restrict__ W, f32x4 acc) {
#pragma unroll
  for (int kt = 0; kt < 8; ++kt) {
    const short8 a = *(const short8*)(X + kt * 32);
    const short8 b = *(const short8*)(W + kt * 32);
    acc = __builtin_amdgcn_mfma_f32_16x16x32_bf16(a, b, acc, 0, 0, 0);
  }
  return acc;
}

__global__ __launch_bounds__(256, 4) void k_mega(
    const float* __restrict__ nf, const int* __restrict__ seg,
    const float* __restrict__ logit_w, const float* __restrict__ logit_b,
    const float* __restrict__ proj_w, const float* __restrict__ proj_b,
    const float* __restrict__ w_ih, const float* __restrict__ w_hh,
    const float* __restrict__ b_ih, const float* __restrict__ b_hh,
    float* __restrict__ gf, int* __restrict__ bar, int* __restrict__ start,
    u16* __restrict__ nbf, float* __restrict__ d0, float* __restrict__ d1,
    float* __restrict__ abuf, u16* __restrict__ hhi, u16* __restrict__ hlo,
    u16* __restrict__ wnsbf, u16* __restrict__ ctxbf,
    float* __restrict__ gibuf, float* __restrict__ ghbuf,
    u16* __restrict__ wihbf, u16* __restrict__ whhbf, u16* __restrict__ whhlo,
    u16* __restrict__ pwtbf) {
  __shared__ char smem[8 * FD * 4];           // 8 KB, aliased per phase
  __shared__ float sden[4];
  float* redf = (float*)smem;
  const int b = blockIdx.x, tid = threadIdx.x;
  const int gtid = b * 256 + tid;             // 0..262143 == V exactly
  const int lane = tid & 63, wv = tid >> 6;

  // ---------------- P0: bounds + weight conversions + proj transpose ----------
  {
    const int v = gtid;
    const int s = seg[v];
    if (v == 0) {
      for (int g = 0; g <= s; ++g) start[g] = 0;
    } else {
      const int p = seg[v - 1];
      for (int g = p + 1; g <= s; ++g) start[g] = v;
    }
    if (v == V_NODES - 1)
      for (int g = s + 1; g <= NGRAPH; ++g) start[g] = V_NODES;
  }
  {
    const int nchunk = TSTEPS * 768 * FD / 4;  // 98304 float4 chunks
    if (gtid < nchunk) {
      const float4 x = ((const float4*)w_ih)[gtid];
      uint2 u; u.x = pkbf(x.x, x.y); u.y = pkbf(x.z, x.w);
      ((uint2*)wihbf)[gtid] = u;
      const float4 y = ((const float4*)w_hh)[gtid];
      uint2 hi_, lo_;
      const u16 h0 = f2bf(y.x), h1 = f2bf(y.y), h2 = f2bf(y.z), h3 = f2bf(y.w);
      hi_.x = (unsigned)h0 | ((unsigned)h1 << 16);
      hi_.y = (unsigned)h2 | ((unsigned)h3 << 16);
      lo_.x = pkbf(y.x - bf2f(h0), y.y - bf2f(h1));
      lo_.y = pkbf(y.z - bf2f(h2), y.w - bf2f(h3));
      ((uint2*)whhbf)[gtid] = hi_;
      ((uint2*)whhlo)[gtid] = lo_;
    }
  }
  if (b < 2 * 64) {  // proj_w [k][n] -> bf16 [n][k]: 64 32x32 tiles per t
    float (*tl)[33] = (float(*)[33])smem;
    const int t = b >> 6, tile = b & 63, bx = tile & 7, by = tile >> 3;
    const int tx = tid & 31, ty = tid >> 5;  // 32 x 8
    const float* S = proj_w + (size_t)t * FD * FD;
    u16* D = pwtbf + (size_t)t * FD * FD;
#pragma unroll
    for (int i = 0; i < 32; i += 8)
      tl[ty + i][tx] = S[(size_t)(by * 32 + ty + i) * FD + bx * 32 + tx];
    __syncthreads();
#pragma unroll
    for (int i = 0; i < 32; i += 8)
      D[(size_t)(bx * 32 + ty + i) * FD + by * 32 + tx] = f2bf(tl[tx][ty + i]);
  }
  gsync(bar, 0);

  // ---------------- P1: per-graph segsum + bf16 nodes + logit dots ------------
  {
    const int h = tid >> 5, sl = tid & 31;  // half-wave per node, 8 feats/lane
    // lwB for feats 8sl..8sl+7, both t
    float wA[8], wB[8];
    {
      const float4 a0 = ((const float4*)(logit_w + FD))[2 * sl];
      const float4 a1 = ((const float4*)(logit_w + FD))[2 * sl + 1];
      const float4 b0 = ((const float4*)(logit_w + 512 + FD))[2 * sl];
      const float4 b1 = ((const float4*)(logit_w + 512 + FD))[2 * sl + 1];
      wA[0]=a0.x; wA[1]=a0.y; wA[2]=a0.z; wA[3]=a0.w;
      wA[4]=a1.x; wA[5]=a1.y; wA[6]=a1.z; wA[7]=a1.w;
      wB[0]=b0.x; wB[1]=b0.y; wB[2]=b0.z; wB[3]=b0.w;
      wB[4]=b1.x; wB[5]=b1.y; wB[6]=b1.z; wB[7]=b1.w;
    }
    for (int gl = 0; gl < 4; ++gl) {
      const int g = b * 4 + gl;
      const int s = start[g], e = start[g + 1];
      float ac[8];
#pragma unroll
      for (int j = 0; j < 8; ++j) ac[j] = 0.f;
      const float4* nfv = (const float4*)nf;
      for (int v = s + h; v < e; v += 8) {
        const float4 x0 = nfv[(size_t)v * 64 + 2 * sl];
        const float4 x1 = nfv[(size_t)v * 64 + 2 * sl + 1];
        ac[0]+=x0.x; ac[1]+=x0.y; ac[2]+=x0.z; ac[3]+=x0.w;
        ac[4]+=x1.x; ac[5]+=x1.y; ac[6]+=x1.z; ac[7]+=x1.w;
        uint4 u;
        u.x = pkbf(x0.x, x0.y); u.y = pkbf(x0.z, x0.w);
        u.z = pkbf(x1.x, x1.y); u.w = pkbf(x1.z, x1.w);
        ((uint4*)(nbf + (size_t)v * FD))[sl] = u;
        float dA = fmaf(x0.x, wA[0], fmaf(x0.y, wA[1], fmaf(x0.z, wA[2], x0.w * wA[3])));
        dA = fmaf(x1.x, wA[4], fmaf(x1.y, wA[5], fmaf(x1.z, wA[6], fmaf(x1.w, wA[7], dA))));
        float dB = fmaf(x0.x, wB[0], fmaf(x0.y, wB[1], fmaf(x0.z, wB[2], x0.w * wB[3])));
        dB = fmaf(x1.x, wB[4], fmaf(x1.y, wB[5], fmaf(x1.z, wB[6], fmaf(x1.w, wB[7], dB))));
#pragma unroll
        for (int off = 1; off < 32; off <<= 1) {
          dA += __shfl_xor(dA, off, 64);
          dB += __shfl_xor(dB, off, 64);
        }
        if (sl == 0) { d0[v] = dA; d1[v] = dB; }
      }
      ((float4*)&redf[h * FD + sl * 8])[0] = make_float4(ac[0], ac[1], ac[2], ac[3]);
      ((float4*)&redf[h * FD + sl * 8])[1] = make_float4(ac[4], ac[5], ac[6], ac[7]);
      __syncthreads();
      float sum = 0.f;
#pragma unroll
      for (int j = 0; j < 8; ++j) sum += redf[j * FD + tid];
      const size_t idx = (size_t)g * FD + tid;
      gf[idx] = sum;
      const u16 hb = f2bf(sum);
      hhi[idx] = hb;
      hlo[idx] = f2bf(sum - bf2f(hb));
      __syncthreads();
    }
  }

  // ---------------- time-step loop -------------------------------------------
  for (int t = 0; t < TSTEPS; ++t) {
    __syncthreads();
    // P2: softmax weights, one wave per graph (block-local)
    {
      const int g = b * 4 + wv;
      const int s = start[g], e = start[g + 1];
      const float lb = logit_b[t];
      const float* dt = t ? d1 : d0;
      const float4 hv = ((const float4*)gf)[(size_t)g * 64 + lane];
      const float4 wa = ((const float4*)(logit_w + (size_t)t * 512))[lane];
      float c = fmaf(fmaxf(hv.x, 0.f), wa.x, fmaf(fmaxf(hv.y, 0.f), wa.y,
                fmaf(fmaxf(hv.z, 0.f), wa.z, fmaxf(hv.w, 0.f) * wa.w)));
#pragma unroll
      for (int off = 1; off < 64; off <<= 1) c += __shfl_xor(c, off, 64);
      float m = -1e30f;
      for (int v = s + lane; v < e; v += 64) {
        const float z = softplus2(c + dt[v] + lb);
        abuf[v] = z;
        m = fmaxf(m, z);
      }
#pragma unroll
      for (int off = 1; off < 64; off <<= 1) m = fmaxf(m, __shfl_xor(m, off, 64));
      float ls = 0.f;
      for (int v = s + lane; v < e; v += 64) {
        const float ez = __expf(abuf[v] - m);
        abuf[v] = ez;
        ls += ez;
      }
#pragma unroll
      for (int off = 1; off < 64; off <<= 1) ls += __shfl_xor(ls, off, 64);
      if (lane == 0) sden[wv] = ls;
    }
    __syncthreads();
    // P3: streaming weighted node sum (block-local graphs)
    {
      const int half = lane >> 5, fl = lane & 31;
      for (int gl = 0; gl < 4; ++gl) {
        const int g = b * 4 + gl;
        const int s = start[g], e = start[g + 1];
        float acc[8];
#pragma unroll
        for (int j = 0; j < 8; ++j) acc[j] = 0.f;
        for (int v0 = s + 2 * wv + half; v0 < e; v0 += 8) {
          const uint4 u = ((const uint4*)(nbf + (size_t)v0 * FD))[fl];
          const float ev = abuf[v0];
          acc[0] = fmaf(ev, bf2f((u16)(u.x & 0xffff)), acc[0]);
          acc[1] = fmaf(ev, bf2f((u16)(u.x >> 16)),    acc[1]);
          acc[2] = fmaf(ev, bf2f((u16)(u.y & 0xffff)), acc[2]);
          acc[3] = fmaf(ev, bf2f((u16)(u.y >> 16)),    acc[3]);
          acc[4] = fmaf(ev, bf2f((u16)(u.z & 0xffff)), acc[4]);
          acc[5] = fmaf(ev, bf2f((u16)(u.z >> 16)),    acc[5]);
          acc[6] = fmaf(ev, bf2f((u16)(u.w & 0xffff)), acc[6]);
          acc[7] = fmaf(ev, bf2f((u16)(u.w >> 16)),    acc[7]);
        }
#pragma unroll
        for (int j = 0; j < 8; ++j) acc[j] += __shfl_xor(acc[j], 32, 64);
        if (half == 0) {
#pragma unroll
          for (int j = 0; j < 8; ++j) redf[wv * FD + fl * 8 + j] = acc[j];
        }
        __syncthreads();
        const float num = redf[tid] + redf[FD + tid] + redf[2 * FD + tid] + redf[3 * FD + tid];
        wnsbf[(size_t)g * FD + tid] = f2bf((e > s) ? (num / sden[gl]) : 0.0f);
        __syncthreads();
      }
    }
    gsync(bar, 1 + t * 3);
    // P4a: ctx = elu(wns @ proj_w^T(bf16 [n][k]) + proj_b)   (4096 tiles, 1/wave)
    {
      const int wid = b * 4 + wv;
      const int mt = wid >> 4, nt = wid & 15;
      const int r = lane & 15, q = lane >> 4;
      f32x4 acc = {0.f, 0.f, 0.f, 0.f};
      acc = mm256(wnsbf + (size_t)(mt * 16 + r) * FD + q * 8,
                  pwtbf + (size_t)t * FD * FD + (size_t)(nt * 16 + r) * FD + q * 8, acc);
      const int gcol = nt * 16 + r;
      const float bs = proj_b[t * FD + gcol];
      const int row0 = mt * 16 + q * 4;
#pragma unroll
      for (int i = 0; i < 4; ++i) {
        float v = acc[i] + bs;
        v = (v > 0.0f) ? v : expm1f(v);
        ctxbf[(size_t)(row0 + i) * FD + gcol] = f2bf(v);
      }
    }
    gsync(bar, 2 + t * 3);
    // P4b: gi = ctx @ w_ih^T + b_ih ; gh = h @ w_hh^T + b_hh (split)  (3 tiles/wave each)
    {
      const int wid = b * 4 + wv;
      const int r = lane & 15, q = lane >> 4;
      const u16* wih_t = wihbf + (size_t)t * 768 * FD;
      const u16* whh_t = whhbf + (size_t)t * 768 * FD;
      const u16* whl_t = whhlo + (size_t)t * 768 * FD;
#pragma unroll
      for (int j = 0; j < 3; ++j) {
        const int id = wid + j * 4096;          // 12288 tiles: 256 row x 48 col
        const int mt = id & 255, nt = id >> 8;
        const int gcol = nt * 16 + r;
        const int row0 = mt * 16 + q * 4;
        const size_t xoff = (size_t)(mt * 16 + r) * FD + q * 8;
        const size_t woff = (size_t)gcol * FD + q * 8;
        f32x4 ai = {0.f, 0.f, 0.f, 0.f};
        ai = mm256(ctxbf + xoff, wih_t + woff, ai);
        const float bi = b_ih[t * 768 + gcol];
#pragma unroll
        for (int i = 0; i < 4; ++i)
          gibuf[(size_t)(row0 + i) * 768 + gcol] = ai[i] + bi;
        f32x4 ah = {0.f, 0.f, 0.f, 0.f};
        ah = mm256(hhi + xoff, whh_t + woff, ah);
        ah = mm256(hlo + xoff, whh_t + woff, ah);
        ah = mm256(hhi + xoff, whl_t + woff, ah);
        const float bh = b_hh[t * 768 + gcol];
#pragma unroll
        for (int i = 0; i < 4; ++i)
          ghbuf[(size_t)(row0 + i) * 768 + gcol] = ah[i] + bh;
      }
    }
    gsync(bar, 3 + t * 3);
    // P5: GRU combine (block-local graphs) + bf16 hi/lo for next step
    for (int gl = 0; gl < 4; ++gl) {
      const int g = b * 4 + gl;
      const float* gir = gibuf + (size_t)g * 768;
      const float* ghr = ghbuf + (size_t)g * 768;
      const float ir = gir[tid], iz = gir[256 + tid], in_ = gir[512 + tid];
      const float hr = ghr[tid], hz = ghr[256 + tid], hn = ghr[512 + tid];
      const float rr = 1.0f / (1.0f + __expf(-(ir + hr)));
      const float zz = 1.0f / (1.0f + __expf(-(iz + hz)));
      const float nn = tanhf(in_ + rr * hn);
      const size_t idx = (size_t)g * FD + tid;
      const float hv = gf[idx];
      const float hnew = (1.0f - zz) * nn + zz * hv;
      gf[idx] = hnew;
      const u16 hb = f2bf(hnew);
      hhi[idx] = hb;
      hlo[idx] = f2bf(hnew - bf2f(hb));
    }
  }
}

extern "C" void kernel_launch(void* const* d_in, const int* in_sizes, int n_in,
                              void* d_out, int out_size, void* d_ws, size_t ws_size,
                              hipStream_t stream) {
  const float* node    = (const float*)d_in[0];
  const int*   seg     = (const int*)d_in[1];
  const float* logit_w = (const float*)d_in[3];
  const float* logit_b = (const float*)d_in[4];
  const float* proj_w  = (const float*)d_in[5];
  const float* proj_b  = (const float*)d_in[6];
  const float* w_ih    = (const float*)d_in[7];
  const float* w_hh    = (const float*)d_in[8];
  const float* b_ih    = (const float*)d_in[9];
  const float* b_hh    = (const float*)d_in[10];
  float* gfeats = (float*)d_out;

  char* p = (char*)d_ws;
  int* bar     = (int*)p;   p += 256;
  int* start   = (int*)p;   p += (((NGRAPH + 1) * sizeof(int)) + 255) & ~(size_t)255;
  u16* nbf     = (u16*)p;   p += (size_t)V_NODES * FD * 2;
  float* d0    = (float*)p; p += (size_t)V_NODES * 4;
  float* d1    = (float*)p; p += (size_t)V_NODES * 4;
  float* abuf  = (float*)p; p += (size_t)V_NODES * 4;
  u16* hhi     = (u16*)p;   p += (size_t)NGRAPH * FD * 2;
  u16* hlo     = (u16*)p;   p += (size_t)NGRAPH * FD * 2;
  u16* wnsbf   = (u16*)p;   p += (size_t)NGRAPH * FD * 2;
  u16* ctxbf   = (u16*)p;   p += (size_t)NGRAPH * FD * 2;
  float* gi    = (float*)p; p += (size_t)NGRAPH * 768 * 4;
  float* gh    = (float*)p; p += (size_t)NGRAPH * 768 * 4;
  u16* wihbf   = (u16*)p;   p += (size_t)TSTEPS * 768 * FD * 2;
  u16* whhbf   = (u16*)p;   p += (size_t)TSTEPS * 768 * FD * 2;
  u16* whhlo   = (u16*)p;   p += (size_t)TSTEPS * 768 * FD * 2;
  u16* pwtbf   = (u16*)p;   p += (size_t)TSTEPS * FD * FD * 2;
  (void)ws_size; (void)in_sizes; (void)n_in; (void)out_size;

  hipMemsetAsync(bar, 0, 256, stream);
  k_mega<<<dim3(NBLK), dim3(256), 0, stream>>>(
      node, seg, logit_w, logit_b, proj_w, proj_b, w_ih, w_hh, b_ih, b_hh,
      gfeats, bar, start, nbf, d0, d1, abuf, hhi, hlo, wnsbf, ctxbf,
      gi, gh, wihbf, whhbf, whhlo, pwtbf);
}

// Round 5
// 598.516 us; speedup vs baseline: 3.1077x; 3.1077x over previous
//
#include <hip/hip_runtime.h>
#include <hip/hip_bf16.h>
#include <math.h>

#define V_NODES 262144
#define NGRAPH  4096
#define FD      256
#define TSTEPS  2
#define GP      16     // graphs per k_steps block
#define SB      512    // k_steps block size (8 waves, 16 half-waves)
#define RS      264    // padded LDS row stride (u16) — 528B = 33*16B, +4-bank skew

typedef unsigned short u16;
typedef __attribute__((ext_vector_type(8))) short short8;
typedef __attribute__((ext_vector_type(4))) float f32x4;

__device__ __forceinline__ float bf2f(u16 u) {
  union { unsigned int i; float f; } x; x.i = ((unsigned int)u) << 16; return x.f;
}
__device__ __forceinline__ u16 f2bf(float f) {
  union { unsigned int i; float f; } x; x.f = f;
  unsigned int r = x.i + 0x7FFFu + ((x.i >> 16) & 1u);
  return (u16)(r >> 16);
}
__device__ __forceinline__ unsigned int pkbf(float a, float b) {
  return (unsigned int)f2bf(a) | ((unsigned int)f2bf(b) << 16);
}
__device__ __forceinline__ float softplus2(float x) {
  return fmaxf(x, 0.0f) + log1pf(__expf(-fabsf(x))) - 0.69314718056f;
}

// ---- K0: bounds + weight conversions + proj transpose (one launch)
__global__ __launch_bounds__(256) void k_prep(
    const int* __restrict__ seg, const float* __restrict__ w_ih,
    const float* __restrict__ w_hh, const float* __restrict__ proj_w,
    int* __restrict__ start, u16* __restrict__ wihbf, u16* __restrict__ whhbf,
    u16* __restrict__ whhlo, u16* __restrict__ pwtbf) {
  __shared__ float tl[32][33];
  const int b = blockIdx.x, tid = threadIdx.x;
  const int gtid = b * 256 + tid;  // 0..262143
  {
    const int v = gtid;
    const int s = seg[v];
    if (v == 0) {
      for (int g = 0; g <= s; ++g) start[g] = 0;
    } else {
      const int p = seg[v - 1];
      for (int g = p + 1; g <= s; ++g) start[g] = v;
    }
    if (v == V_NODES - 1)
      for (int g = s + 1; g <= NGRAPH; ++g) start[g] = V_NODES;
  }
  {
    const int nchunk = TSTEPS * 768 * FD / 4;  // 98304
    if (gtid < nchunk) {
      const float4 x = ((const float4*)w_ih)[gtid];
      uint2 u; u.x = pkbf(x.x, x.y); u.y = pkbf(x.z, x.w);
      ((uint2*)wihbf)[gtid] = u;
      const float4 y = ((const float4*)w_hh)[gtid];
      const u16 h0 = f2bf(y.x), h1 = f2bf(y.y), h2 = f2bf(y.z), h3 = f2bf(y.w);
      uint2 hi_, lo_;
      hi_.x = (unsigned)h0 | ((unsigned)h1 << 16);
      hi_.y = (unsigned)h2 | ((unsigned)h3 << 16);
      lo_.x = pkbf(y.x - bf2f(h0), y.y - bf2f(h1));
      lo_.y = pkbf(y.z - bf2f(h2), y.w - bf2f(h3));
      ((uint2*)whhbf)[gtid] = hi_;
      ((uint2*)whhlo)[gtid] = lo_;
    }
  }
  if (b < 2 * 64) {  // proj_w [k][n] -> bf16 [n][k]
    const int t = b >> 6, tile = b & 63, bx = tile & 7, by = tile >> 3;
    const int tx = tid & 31, ty = tid >> 5;  // 32 x 8
    const float* S = proj_w + (size_t)t * FD * FD;
    u16* D = pwtbf + (size_t)t * FD * FD;
#pragma unroll
    for (int i = 0; i < 32; i += 8)
      tl[ty + i][tx] = S[(size_t)(by * 32 + ty + i) * FD + bx * 32 + tx];
    __syncthreads();
#pragma unroll
    for (int i = 0; i < 32; i += 8)
      D[(size_t)(bx * 32 + ty + i) * FD + by * 32 + tx] = f2bf(tl[tx][ty + i]);
  }
}

// ---- K1: block per graph: segsum -> gf, bf16 node copy, both logit dots.
__global__ __launch_bounds__(256) void k_pass1(
    const float* __restrict__ nf, const int* __restrict__ start,
    const float* __restrict__ logit_w, float* __restrict__ gf,
    u16* __restrict__ nbf, float* __restrict__ d0, float* __restrict__ d1) {
  __shared__ __align__(16) float redf[8][FD];
  const int g = blockIdx.x, tid = threadIdx.x;
  const int h = tid >> 5, sl = tid & 31;  // 8 half-waves, 8 feats/lane
  const int s = start[g], e = start[g + 1];
  float wA[8], wB[8];
  {
    const float4 a0 = ((const float4*)(logit_w + FD))[2 * sl];
    const float4 a1 = ((const float4*)(logit_w + FD))[2 * sl + 1];
    const float4 b0 = ((const float4*)(logit_w + 512 + FD))[2 * sl];
    const float4 b1 = ((const float4*)(logit_w + 512 + FD))[2 * sl + 1];
    wA[0]=a0.x; wA[1]=a0.y; wA[2]=a0.z; wA[3]=a0.w;
    wA[4]=a1.x; wA[5]=a1.y; wA[6]=a1.z; wA[7]=a1.w;
    wB[0]=b0.x; wB[1]=b0.y; wB[2]=b0.z; wB[3]=b0.w;
    wB[4]=b1.x; wB[5]=b1.y; wB[6]=b1.z; wB[7]=b1.w;
  }
  float ac[8];
#pragma unroll
  for (int j = 0; j < 8; ++j) ac[j] = 0.f;
  const float4* nfv = (const float4*)nf;
  for (int v = s + h; v < e; v += 8) {
    const float4 x0 = nfv[(size_t)v * 64 + 2 * sl];
    const float4 x1 = nfv[(size_t)v * 64 + 2 * sl + 1];
    ac[0]+=x0.x; ac[1]+=x0.y; ac[2]+=x0.z; ac[3]+=x0.w;
    ac[4]+=x1.x; ac[5]+=x1.y; ac[6]+=x1.z; ac[7]+=x1.w;
    uint4 u;
    u.x = pkbf(x0.x, x0.y); u.y = pkbf(x0.z, x0.w);
    u.z = pkbf(x1.x, x1.y); u.w = pkbf(x1.z, x1.w);
    ((uint4*)(nbf + (size_t)v * FD))[sl] = u;
    float dA = fmaf(x0.x, wA[0], fmaf(x0.y, wA[1], fmaf(x0.z, wA[2], x0.w * wA[3])));
    dA = fmaf(x1.x, wA[4], fmaf(x1.y, wA[5], fmaf(x1.z, wA[6], fmaf(x1.w, wA[7], dA))));
    float dB = fmaf(x0.x, wB[0], fmaf(x0.y, wB[1], fmaf(x0.z, wB[2], x0.w * wB[3])));
    dB = fmaf(x1.x, wB[4], fmaf(x1.y, wB[5], fmaf(x1.z, wB[6], fmaf(x1.w, wB[7], dB))));
#pragma unroll
    for (int off = 1; off < 32; off <<= 1) {
      dA += __shfl_xor(dA, off, 64);
      dB += __shfl_xor(dB, off, 64);
    }
    if (sl == 0) { d0[v] = dA; d1[v] = dB; }
  }
  ((float4*)&redf[h][sl * 8])[0] = make_float4(ac[0], ac[1], ac[2], ac[3]);
  ((float4*)&redf[h][sl * 8])[1] = make_float4(ac[4], ac[5], ac[6], ac[7]);
  __syncthreads();
  float sum = 0.f;
#pragma unroll
  for (int j = 0; j < 8; ++j) sum += redf[j][tid];
  gf[(size_t)g * FD + tid] = sum;
}

// ---- K2: whole time loop; block owns GP=16 contiguous graphs. No cross-block deps.
__global__ __launch_bounds__(SB, 1) void k_steps(
    const int* __restrict__ start, const float* __restrict__ logit_w,
    const float* __restrict__ logit_b, const float* __restrict__ proj_b,
    const float* __restrict__ b_ih, const float* __restrict__ b_hh,
    const u16* __restrict__ nbf, const float* __restrict__ d0,
    const float* __restrict__ d1, float* __restrict__ gf,
    float* __restrict__ gibuf, float* __restrict__ ghbuf,
    const u16* __restrict__ wihbf, const u16* __restrict__ whhbf,
    const u16* __restrict__ whhlo, const u16* __restrict__ pwtbf) {
  __shared__ __align__(16) float ew[2560];          // softmax weights, all local nodes
  __shared__ __align__(16) float redf[GP * FD];     // wsum cross-halfwave results
  __shared__ __align__(16) u16 wns_s[GP * RS];
  __shared__ __align__(16) u16 ctx_s[GP * RS];
  __shared__ __align__(16) u16 hhi_s[GP * RS];
  __shared__ __align__(16) u16 hlo_s[GP * RS];
  const int b = blockIdx.x, tid = threadIdx.x;
  const int lane = tid & 63, wv = tid >> 6;        // 8 waves
  const int half = lane >> 5, sl = lane & 31;      // 16 half-waves
  const int g0 = b * GP;
  const int vs = start[g0];
  const int hw = wv * 2 + half;                    // local graph owned by this half-wave
  const int g = g0 + hw;
  const int s = start[g], e = start[g + 1];

  for (int t = 0; t < TSTEPS; ++t) {
    // ---- h -> bf16 hi/lo in LDS
    for (int i = tid; i < GP * FD; i += SB) {
      const float x = gf[(size_t)g0 * FD + i];
      const u16 hb = f2bf(x);
      const int row = i >> 8, f = i & 255;
      hhi_s[row * RS + f] = hb;
      hlo_s[row * RS + f] = f2bf(x - bf2f(hb));
    }
    __syncthreads();
    // ---- P2+P3 fused (half-wave per graph): softmax weights then wsum stream
    {
      const float lb = logit_b[t];
      const float* dt = t ? d1 : d0;
      const float* lwA = logit_w + (size_t)t * 512;
      const float4 h0 = ((const float4*)(gf + (size_t)g * FD))[2 * sl];
      const float4 h1 = ((const float4*)(gf + (size_t)g * FD))[2 * sl + 1];
      const float4 wa0 = ((const float4*)lwA)[2 * sl];
      const float4 wa1 = ((const float4*)lwA)[2 * sl + 1];
      float c = fmaf(fmaxf(h0.x, 0.f), wa0.x, fmaf(fmaxf(h0.y, 0.f), wa0.y,
                fmaf(fmaxf(h0.z, 0.f), wa0.z, fmaxf(h0.w, 0.f) * wa0.w)));
      c = fmaf(fmaxf(h1.x, 0.f), wa1.x, fmaf(fmaxf(h1.y, 0.f), wa1.y,
          fmaf(fmaxf(h1.z, 0.f), wa1.z, fmaf(fmaxf(h1.w, 0.f), wa1.w, c))));
#pragma unroll
      for (int off = 1; off < 32; off <<= 1) c += __shfl_xor(c, off, 64);
      float m = -1e30f;
      for (int v = s + sl; v < e; v += 32) {
        const float z = softplus2(c + dt[v] + lb);
        ew[v - vs] = z;
        m = fmaxf(m, z);
      }
#pragma unroll
      for (int off = 1; off < 32; off <<= 1) m = fmaxf(m, __shfl_xor(m, off, 64));
      float ls = 0.f;
      for (int v = s + sl; v < e; v += 32) {
        const float ezz = __expf(ew[v - vs] - m);
        ew[v - vs] = ezz;
        ls += ezz;
      }
#pragma unroll
      for (int off = 1; off < 32; off <<= 1) ls += __shfl_xor(ls, off, 64);
      const float inv = (e > s) ? 1.0f / ls : 0.f;
      for (int v = s + sl; v < e; v += 32) ew[v - vs] *= inv;
      // stream wsum for my graph: lane sl covers feats 8sl..8sl+7 (full row/half-wave)
      float acc[8];
#pragma unroll
      for (int j = 0; j < 8; ++j) acc[j] = 0.f;
      for (int v = s; v < e; ++v) {
        const uint4 u = ((const uint4*)(nbf + (size_t)v * FD))[sl];
        const float a = ew[v - vs];
        acc[0] = fmaf(a, bf2f((u16)(u.x & 0xffff)), acc[0]);
        acc[1] = fmaf(a, bf2f((u16)(u.x >> 16)),    acc[1]);
        acc[2] = fmaf(a, bf2f((u16)(u.y & 0xffff)), acc[2]);
        acc[3] = fmaf(a, bf2f((u16)(u.y >> 16)),    acc[3]);
        acc[4] = fmaf(a, bf2f((u16)(u.z & 0xffff)), acc[4]);
        acc[5] = fmaf(a, bf2f((u16)(u.z >> 16)),    acc[5]);
        acc[6] = fmaf(a, bf2f((u16)(u.w & 0xffff)), acc[6]);
        acc[7] = fmaf(a, bf2f((u16)(u.w >> 16)),    acc[7]);
      }
      ((float4*)&redf[hw * FD + sl * 8])[0] = make_float4(acc[0], acc[1], acc[2], acc[3]);
      ((float4*)&redf[hw * FD + sl * 8])[1] = make_float4(acc[4], acc[5], acc[6], acc[7]);
    }
    __syncthreads();
    for (int i = tid; i < GP * FD; i += SB)
      wns_s[(i >> 8) * RS + (i & 255)] = f2bf(redf[i]);
    __syncthreads();
    // ---- P4a: ctx = elu(wns @ proj_w^T + proj_b); 16 tiles, 2/wave
    {
      const int r = lane & 15, q = lane >> 4;
      const u16* xp = wns_s + r * RS + q * 8;
#pragma unroll
      for (int jj = 0; jj < 2; ++jj) {
        const int nt = wv * 2 + jj;
        const u16* wp = pwtbf + (size_t)t * FD * FD + (size_t)(nt * 16 + r) * FD + q * 8;
        f32x4 a4 = {0.f, 0.f, 0.f, 0.f};
#pragma unroll
        for (int kt = 0; kt < 8; ++kt) {
          const short8 av = *(const short8*)(xp + kt * 32);
          const short8 bv = *(const short8*)(wp + kt * 32);
          a4 = __builtin_amdgcn_mfma_f32_16x16x32_bf16(av, bv, a4, 0, 0, 0);
        }
        const int gcol = nt * 16 + r;
        const float bs = proj_b[t * FD + gcol];
#pragma unroll
        for (int i = 0; i < 4; ++i) {
          float v = a4[i] + bs;
          v = (v > 0.0f) ? v : expm1f(v);
          ctx_s[(q * 4 + i) * RS + gcol] = f2bf(v);
        }
      }
    }
    __syncthreads();
    // ---- P4b: gi = ctx@wih^T + b_ih ; gh = h@whh^T + b_hh (split); 48 tiles, 6/wave
    {
      const int r = lane & 15, q = lane >> 4;
      const u16* wih_t = wihbf + (size_t)t * 768 * FD;
      const u16* whh_t = whhbf + (size_t)t * 768 * FD;
      const u16* whl_t = whhlo + (size_t)t * 768 * FD;
      const u16* xi = ctx_s + r * RS + q * 8;
      const u16* xh = hhi_s + r * RS + q * 8;
      const u16* xl = hlo_s + r * RS + q * 8;
#pragma unroll
      for (int j = 0; j < 6; ++j) {
        const int nt = wv * 6 + j;
        const int gcol = nt * 16 + r;
        const u16* wi = wih_t + (size_t)gcol * FD + q * 8;
        const u16* wh = whh_t + (size_t)gcol * FD + q * 8;
        const u16* wl = whl_t + (size_t)gcol * FD + q * 8;
        f32x4 ai = {0.f, 0.f, 0.f, 0.f};
        f32x4 ah = {0.f, 0.f, 0.f, 0.f};
#pragma unroll
        for (int kt = 0; kt < 8; ++kt) {
          const short8 bi = *(const short8*)(wi + kt * 32);
          const short8 aiv = *(const short8*)(xi + kt * 32);
          ai = __builtin_amdgcn_mfma_f32_16x16x32_bf16(aiv, bi, ai, 0, 0, 0);
          const short8 bh = *(const short8*)(wh + kt * 32);
          const short8 xhh = *(const short8*)(xh + kt * 32);
          const short8 xll = *(const short8*)(xl + kt * 32);
          ah = __builtin_amdgcn_mfma_f32_16x16x32_bf16(xhh, bh, ah, 0, 0, 0);
          ah = __builtin_amdgcn_mfma_f32_16x16x32_bf16(xll, bh, ah, 0, 0, 0);
          const short8 bl = *(const short8*)(wl + kt * 32);
          ah = __builtin_amdgcn_mfma_f32_16x16x32_bf16(xhh, bl, ah, 0, 0, 0);
        }
        const float bi_ = b_ih[t * 768 + gcol];
        const float bh_ = b_hh[t * 768 + gcol];
#pragma unroll
        for (int i = 0; i < 4; ++i) {
          gibuf[(size_t)(g0 + q * 4 + i) * 768 + gcol] = ai[i] + bi_;
          ghbuf[(size_t)(g0 + q * 4 + i) * 768 + gcol] = ah[i] + bh_;
        }
      }
    }
    __syncthreads();
    // ---- P5: GRU combine -> gf
    for (int i = tid; i < GP * FD; i += SB) {
      const int lg = i >> 8, f = i & 255;
      const size_t gr = (size_t)(g0 + lg) * 768;
      const float ir = gibuf[gr + f], iz = gibuf[gr + 256 + f], in_ = gibuf[gr + 512 + f];
      const float hr = ghbuf[gr + f], hz = ghbuf[gr + 256 + f], hn = ghbuf[gr + 512 + f];
      const float rr = 1.0f / (1.0f + __expf(-(ir + hr)));
      const float zz = 1.0f / (1.0f + __expf(-(iz + hz)));
      const float nn = tanhf(in_ + rr * hn);
      const size_t idx = (size_t)g0 * FD + i;
      gf[idx] = (1.0f - zz) * nn + zz * gf[idx];
    }
    __syncthreads();
  }
}

extern "C" void kernel_launch(void* const* d_in, const int* in_sizes, int n_in,
                              void* d_out, int out_size, void* d_ws, size_t ws_size,
                              hipStream_t stream) {
  const float* node    = (const float*)d_in[0];
  const int*   seg     = (const int*)d_in[1];
  const float* logit_w = (const float*)d_in[3];
  const float* logit_b = (const float*)d_in[4];
  const float* proj_w  = (const float*)d_in[5];
  const float* proj_b  = (const float*)d_in[6];
  const float* w_ih    = (const float*)d_in[7];
  const float* w_hh    = (const float*)d_in[8];
  const float* b_ih    = (const float*)d_in[9];
  const float* b_hh    = (const float*)d_in[10];
  float* gfeats = (float*)d_out;

  char* p = (char*)d_ws;
  int* start   = (int*)p;   p += (((NGRAPH + 1) * sizeof(int)) + 255) & ~(size_t)255;
  u16* nbf     = (u16*)p;   p += (size_t)V_NODES * FD * 2;
  float* d0    = (float*)p; p += (size_t)V_NODES * 4;
  float* d1    = (float*)p; p += (size_t)V_NODES * 4;
  float* gi    = (float*)p; p += (size_t)NGRAPH * 768 * 4;
  float* gh    = (float*)p; p += (size_t)NGRAPH * 768 * 4;
  u16* wihbf   = (u16*)p;   p += (size_t)TSTEPS * 768 * FD * 2;
  u16* whhbf   = (u16*)p;   p += (size_t)TSTEPS * 768 * FD * 2;
  u16* whhlo   = (u16*)p;   p += (size_t)TSTEPS * 768 * FD * 2;
  u16* pwtbf   = (u16*)p;   p += (size_t)TSTEPS * FD * FD * 2;
  (void)ws_size; (void)in_sizes; (void)n_in; (void)out_size;

  k_prep<<<dim3(V_NODES / 256), dim3(256), 0, stream>>>(
      seg, w_ih, w_hh, proj_w, start, wihbf, whhbf, whhlo, pwtbf);
  k_pass1<<<dim3(NGRAPH), dim3(256), 0, stream>>>(
      node, start, logit_w, gfeats, nbf, d0, d1);
  k_steps<<<dim3(NGRAPH / GP), dim3(SB), 0, stream>>>(
      start, logit_w, logit_b, proj_b, b_ih, b_hh, nbf, d0, d1,
      gfeats, gi, gh, wihbf, whhbf, whhlo, pwtbf);
}